// Round 5
// baseline (31.954 us; speedup 1.0000x reference)
//
#include <hip/hip_runtime.h>

// Flux_Kernels: 5-point stencil with Dirichlet BCs on all 4 sides.
// out[i,j] = D * ( s0*(nUp + nDown + nLeft + nRight) + 4*s1*u[i,j] )
// Off-grid neighbors -> dirichlet_val[{0,1,2,3}] for {i=0, i=NX-1, j=0, j=NY-1}.
//
// Round-5 = round-4 with the nontemporal-store compile fix (clang ext_vector
// float4 instead of HIP_vector_type). One thread owns a 4-row x 8-col strip;
// 12 independent float4 loads issued before compute (12 KiB/wave in flight);
// intra-thread halo free in registers; strip edges via __shfl; lanes 0/63
// patch with prefetched edge scalars. Nontemporal stores keep the write
// stream from evicting u_main (64 MB, L3-resident) from Infinity Cache.

#define NX 4096
#define NY 4096
#define CPT 8                 // cols per thread
#define ROWS 4                // rows per thread
#define TPR (NY / CPT)        // 512 threads per row-band

typedef float float4c __attribute__((ext_vector_type(4)));

__global__ __launch_bounds__(256) void flux_stencil_kernel(
    const float* __restrict__ u,
    const float* __restrict__ D_eff,
    const float* __restrict__ dv,
    const float* __restrict__ st,
    float* __restrict__ out)
{
    const float D  = D_eff[0];
    const float s0 = st[0];
    const float s1 = st[1];
    const float k1 = D * s0;         // neighbor coefficient
    const float k4 = 4.0f * D * s1;  // center coefficient
    const float dvUp = dv[0], dvDn = dv[1], dvL = dv[2], dvR = dv[3];

    const int tid  = blockIdx.x * blockDim.x + threadIdx.x;
    const int band = tid >> 9;             // which 4-row band
    const int cg   = tid & (TPR - 1);      // 8-col group within row
    const int j    = cg << 3;              // starting column
    const int i0   = band * ROWS;          // first row of strip
    const int lane = threadIdx.x & 63;

    const float* rowp = u + (size_t)i0 * NY + j;
    float*       outp = out + (size_t)i0 * NY + j;

    // ---- issue ALL loads first: 6 rows x 2 quads = 12 independent float4 ----
    const float4 r0a = *reinterpret_cast<const float4*>(rowp);
    const float4 r0b = *reinterpret_cast<const float4*>(rowp + 4);
    const float4 r1a = *reinterpret_cast<const float4*>(rowp + NY);
    const float4 r1b = *reinterpret_cast<const float4*>(rowp + NY + 4);
    const float4 r2a = *reinterpret_cast<const float4*>(rowp + 2 * NY);
    const float4 r2b = *reinterpret_cast<const float4*>(rowp + 2 * NY + 4);
    const float4 r3a = *reinterpret_cast<const float4*>(rowp + 3 * NY);
    const float4 r3b = *reinterpret_cast<const float4*>(rowp + 3 * NY + 4);

    const bool topEdge = (i0 == 0);
    const bool botEdge = (i0 + ROWS == NX);
    const float4 rma = topEdge ? make_float4(dvUp, dvUp, dvUp, dvUp)
                               : *reinterpret_cast<const float4*>(rowp - NY);
    const float4 rmb = topEdge ? make_float4(dvUp, dvUp, dvUp, dvUp)
                               : *reinterpret_cast<const float4*>(rowp - NY + 4);
    const float4 r4a = botEdge ? make_float4(dvDn, dvDn, dvDn, dvDn)
                               : *reinterpret_cast<const float4*>(rowp + 4 * NY);
    const float4 r4b = botEdge ? make_float4(dvDn, dvDn, dvDn, dvDn)
                               : *reinterpret_cast<const float4*>(rowp + 4 * NY + 4);

    // edge scalars for wave-boundary lanes (patched after shuffles)
    float lE0 = dvL, lE1 = dvL, lE2 = dvL, lE3 = dvL;
    float rE0 = dvR, rE1 = dvR, rE2 = dvR, rE3 = dvR;
    if (lane == 0 && j != 0) {
        lE0 = rowp[-1];
        lE1 = rowp[NY - 1];
        lE2 = rowp[2 * NY - 1];
        lE3 = rowp[3 * NY - 1];
    }
    if (lane == 63 && j + CPT != NY) {
        rE0 = rowp[CPT];
        rE1 = rowp[NY + CPT];
        rE2 = rowp[2 * NY + CPT];
        rE3 = rowp[3 * NY + CPT];
    }

    // ---- compute + nontemporal store ----
    #define ROW_OUT(UPA, UPB, CA, CB, DNA, DNB, LE, RE, OFS)                   \
    {                                                                          \
        float lft = __shfl_up(CB.w, 1);                                        \
        float rgt = __shfl_down(CA.x, 1);                                      \
        if (lane == 0)  lft = LE;                                              \
        if (lane == 63) rgt = RE;                                              \
        float4c oa, ob;                                                        \
        oa.x = k1 * (UPA.x + DNA.x + lft  + CA.y) + k4 * CA.x;                 \
        oa.y = k1 * (UPA.y + DNA.y + CA.x + CA.z) + k4 * CA.y;                 \
        oa.z = k1 * (UPA.z + DNA.z + CA.y + CA.w) + k4 * CA.z;                 \
        oa.w = k1 * (UPA.w + DNA.w + CA.z + CB.x) + k4 * CA.w;                 \
        ob.x = k1 * (UPB.x + DNB.x + CA.w + CB.y) + k4 * CB.x;                 \
        ob.y = k1 * (UPB.y + DNB.y + CB.x + CB.z) + k4 * CB.y;                 \
        ob.z = k1 * (UPB.z + DNB.z + CB.y + CB.w) + k4 * CB.z;                 \
        ob.w = k1 * (UPB.w + DNB.w + CB.z + rgt ) + k4 * CB.w;                 \
        __builtin_nontemporal_store(oa, reinterpret_cast<float4c*>(outp + (OFS)));       \
        __builtin_nontemporal_store(ob, reinterpret_cast<float4c*>(outp + (OFS) + 4));   \
    }

    ROW_OUT(rma, rmb, r0a, r0b, r1a, r1b, lE0, rE0, 0)
    ROW_OUT(r0a, r0b, r1a, r1b, r2a, r2b, lE1, rE1, NY)
    ROW_OUT(r1a, r1b, r2a, r2b, r3a, r3b, lE2, rE2, 2 * NY)
    ROW_OUT(r2a, r2b, r3a, r3b, r4a, r4b, lE3, rE3, 3 * NY)

    #undef ROW_OUT
}

extern "C" void kernel_launch(void* const* d_in, const int* in_sizes, int n_in,
                              void* d_out, int out_size, void* d_ws, size_t ws_size,
                              hipStream_t stream) {
    const float* u_main    = (const float*)d_in[0];
    // d_in[1] = u_coupled (unused)
    const float* D_eff     = (const float*)d_in[2];
    const float* dirichlet = (const float*)d_in[3];
    const float* stencil   = (const float*)d_in[4];
    // d_in[5] = t (unused)
    float* outp = (float*)d_out;

    const int total_threads = (NX / ROWS) * TPR;   // 524,288
    const int block = 256;
    const int grid = total_threads / block;        // 2048

    flux_stencil_kernel<<<grid, block, 0, stream>>>(u_main, D_eff, dirichlet, stencil, outp);
}

// Round 6
// 27.149 us; speedup vs baseline: 1.1770x; 1.1770x over previous
//
#include <hip/hip_runtime.h>

// Flux_Kernels: 5-point stencil with Dirichlet BCs on all 4 sides.
// out[i,j] = D * ( s0*(nUp + nDown + nLeft + nRight) + 4*s1*u[i,j] )
// Off-grid neighbors -> dirichlet_val[{0,1,2,3}] for {i=0, i=NX-1, j=0, j=NY-1}.
//
// Round-6: CU-byte-throughput model. One thread marches 32 rows x 4 cols with
// an 8-slot rolling register pipeline (prefetch distance 5 rows), cutting the
// vertical-halo read amplification from 1.5x (ROWS=4) to 1.06x. All 64 edge
// scalars (lanes 0/63) are hoisted out of the loop in two batches (stays under
// the 63-outstanding-vmem limit). Plain stores (nt regressed in R5). Bijective
// XCD swizzle: 512 blocks; each XCD gets a contiguous 64-band chunk per
// column-group so vertically-adjacent bands' halo re-reads hit XCD-local L2.

#define NX 4096
#define NY 4096
#define ROWS 32
#define NBUF 8

__global__ __launch_bounds__(256) void flux_stencil_kernel(
    const float* __restrict__ u,
    const float* __restrict__ D_eff,
    const float* __restrict__ dv,
    const float* __restrict__ st,
    float* __restrict__ out)
{
    const float D  = D_eff[0];
    const float s0 = st[0];
    const float s1 = st[1];
    const float k1 = D * s0;         // neighbor coefficient
    const float k4 = 4.0f * D * s1;  // center coefficient
    const float dvUp = dv[0], dvDn = dv[1], dvL = dv[2], dvR = dv[3];

    // XCD-aware bijective swizzle over 512 blocks (8 XCDs assumed = hw%8):
    // x = hw&7 -> cg = x>>1 (column group 0..3), band = (x&1)*64 + hw>>3.
    // Same-cg vertically-adjacent bands differ by hw+8 -> same XCD L2.
    const int hw   = blockIdx.x;
    const int x    = hw & 7;
    const int band = ((x & 1) << 6) + (hw >> 3);   // [0,128)
    const int cg   = x >> 1;                       // [0,4)
    const int w    = threadIdx.x >> 6;             // wave in block [0,4)
    const int lane = threadIdx.x & 63;
    const int j    = cg * 1024 + w * 256 + lane * 4;
    const int i0   = band * ROWS;

    const float* rowp = u   + (size_t)i0 * NY + j;
    float*       outp = out + (size_t)i0 * NY + j;

    // ---- rolling row buffers: buf holds 8 consecutive row-quads ----
    float4 buf[NBUF];
    buf[0] = (i0 == 0) ? make_float4(dvUp, dvUp, dvUp, dvUp)
                       : *reinterpret_cast<const float4*>(rowp - NY);
    #pragma unroll
    for (int k = 0; k < 6; ++k)      // rows i0 .. i0+5 -> buf[1..6]
        buf[k + 1] = *reinterpret_cast<const float4*>(rowp + k * NY);

    // ---- edge scalars for wave-boundary lanes, batch A (rows 0..15) ----
    float le[ROWS], re[ROWS];
    const bool lEdge = (j == 0);
    const bool rEdge = (j + 4 == NY);
    if (lane == 0) {
        #pragma unroll
        for (int k = 0; k < 16; ++k)
            le[k] = lEdge ? dvL : rowp[k * NY - 1];
    }
    if (lane == 63) {
        #pragma unroll
        for (int k = 0; k < 16; ++k)
            re[k] = rEdge ? dvR : rowp[k * NY + 4];
    }

    #pragma unroll
    for (int r = 0; r < ROWS; ++r) {
        if (r == 8) {
            // edge batch B (rows 16..31), issued 8 iterations before first use
            if (lane == 0) {
                #pragma unroll
                for (int k = 16; k < 32; ++k)
                    le[k] = lEdge ? dvL : rowp[k * NY - 1];
            }
            if (lane == 63) {
                #pragma unroll
                for (int k = 16; k < 32; ++k)
                    re[k] = rEdge ? dvR : rowp[k * NY + 4];
            }
        }

        // prefetch row i0+r+6 into buf[(r+7)%NBUF] (used as dn at iter r+5)
        if (r <= 26) {
            const int row = i0 + r + 6;
            buf[(r + 7) % NBUF] =
                (row >= NX) ? make_float4(dvDn, dvDn, dvDn, dvDn)
                            : *reinterpret_cast<const float4*>(rowp + (r + 6) * NY);
        }

        const float4 up = buf[r % NBUF];          // row i0+r-1
        const float4 cc = buf[(r + 1) % NBUF];    // row i0+r
        const float4 dn = buf[(r + 2) % NBUF];    // row i0+r+1

        float lft = __shfl_up(cc.w, 1);
        float rgt = __shfl_down(cc.x, 1);
        if (lane == 0)  lft = le[r];
        if (lane == 63) rgt = re[r];

        float4 o;
        o.x = k1 * (up.x + dn.x + lft  + cc.y) + k4 * cc.x;
        o.y = k1 * (up.y + dn.y + cc.x + cc.z) + k4 * cc.y;
        o.z = k1 * (up.z + dn.z + cc.y + cc.w) + k4 * cc.z;
        o.w = k1 * (up.w + dn.w + cc.z + rgt ) + k4 * cc.w;
        *reinterpret_cast<float4*>(outp + r * NY) = o;
    }
}

extern "C" void kernel_launch(void* const* d_in, const int* in_sizes, int n_in,
                              void* d_out, int out_size, void* d_ws, size_t ws_size,
                              hipStream_t stream) {
    const float* u_main    = (const float*)d_in[0];
    // d_in[1] = u_coupled (unused)
    const float* D_eff     = (const float*)d_in[2];
    const float* dirichlet = (const float*)d_in[3];
    const float* stencil   = (const float*)d_in[4];
    // d_in[5] = t (unused)
    float* outp = (float*)d_out;

    // (4096/ROWS)=128 bands x (4096/4 cols)=1024 threads = 131072 threads
    const int grid  = 512;     // 2 blocks/CU
    const int block = 256;

    flux_stencil_kernel<<<grid, block, 0, stream>>>(u_main, D_eff, dirichlet, stencil, outp);
}

// Round 7
// 27.078 us; speedup vs baseline: 1.1801x; 1.0026x over previous
//
#include <hip/hip_runtime.h>

// Flux_Kernels: 5-point stencil with Dirichlet BCs on all 4 sides.
// out[i,j] = D * ( s0*(nUp + nDown + nLeft + nRight) + 4*s1*u[i,j] )
// Off-grid neighbors -> dirichlet_val[{0,1,2,3}] for {i=0, i=NX-1, j=0, j=NY-1}.
//
// Round-7: R6 structure (rolling 8-slot register pipeline, prefetch distance
// ~5 rows, hoisted edge scalars, XCD swizzle, plain stores) but ROWS=16 and
// grid=1024 -> 4 blocks/CU = 16 waves/CU (R6 had 8; Occupancy was 16% and
// VALUBusy 7.8% => latency-bound, not amplification-bound). Amplification
// rises only 1.06x -> 1.125x (~136 MiB CU traffic, 21.5 us floor at the
// 6.65 TB/s streaming ceiling) while latency-hiding capacity doubles.

#define NX 4096
#define NY 4096
#define ROWS 16
#define NBUF 8

__global__ __launch_bounds__(256) void flux_stencil_kernel(
    const float* __restrict__ u,
    const float* __restrict__ D_eff,
    const float* __restrict__ dv,
    const float* __restrict__ st,
    float* __restrict__ out)
{
    const float D  = D_eff[0];
    const float s0 = st[0];
    const float s1 = st[1];
    const float k1 = D * s0;         // neighbor coefficient
    const float k4 = 4.0f * D * s1;  // center coefficient
    const float dvUp = dv[0], dvDn = dv[1], dvL = dv[2], dvR = dv[3];

    // XCD-aware bijective swizzle over 1024 blocks (XCD = hw%8 assumed):
    // x = hw&7 -> cg = x>>1 (column group 0..3), band = ((x&1)<<7) + (hw>>3).
    // Vertically-adjacent bands (same cg) are hw and hw+8 -> same XCD L2.
    const int hw   = blockIdx.x;
    const int x    = hw & 7;
    const int band = ((x & 1) << 7) + (hw >> 3);   // [0,256)
    const int cg   = x >> 1;                       // [0,4)
    const int w    = threadIdx.x >> 6;             // wave in block [0,4)
    const int lane = threadIdx.x & 63;
    const int j    = cg * 1024 + w * 256 + lane * 4;
    const int i0   = band * ROWS;

    const float* rowp = u   + (size_t)i0 * NY + j;
    float*       outp = out + (size_t)i0 * NY + j;

    // ---- rolling row buffers: buf holds 8 consecutive row-quads ----
    float4 buf[NBUF];
    buf[0] = (i0 == 0) ? make_float4(dvUp, dvUp, dvUp, dvUp)
                       : *reinterpret_cast<const float4*>(rowp - NY);
    #pragma unroll
    for (int k = 0; k < 6; ++k)      // rows i0 .. i0+5 -> buf[1..6]
        buf[k + 1] = *reinterpret_cast<const float4*>(rowp + k * NY);

    // ---- edge scalars for wave-boundary lanes (hoisted, single batch) ----
    float le[ROWS], re[ROWS];
    const bool lEdge = (j == 0);
    const bool rEdge = (j + 4 == NY);
    if (lane == 0) {
        #pragma unroll
        for (int k = 0; k < ROWS; ++k)
            le[k] = lEdge ? dvL : rowp[k * NY - 1];
    }
    if (lane == 63) {
        #pragma unroll
        for (int k = 0; k < ROWS; ++k)
            re[k] = rEdge ? dvR : rowp[k * NY + 4];
    }

    #pragma unroll
    for (int r = 0; r < ROWS; ++r) {
        // prefetch row i0+r+6 into buf[(r+7)%NBUF] (used as dn at iter r+5)
        if (r <= ROWS - 6) {
            const int row = i0 + r + 6;
            buf[(r + 7) % NBUF] =
                (row >= NX) ? make_float4(dvDn, dvDn, dvDn, dvDn)
                            : *reinterpret_cast<const float4*>(rowp + (r + 6) * NY);
        }

        const float4 up = buf[r % NBUF];          // row i0+r-1
        const float4 cc = buf[(r + 1) % NBUF];    // row i0+r
        const float4 dn = buf[(r + 2) % NBUF];    // row i0+r+1

        float lft = __shfl_up(cc.w, 1);
        float rgt = __shfl_down(cc.x, 1);
        if (lane == 0)  lft = le[r];
        if (lane == 63) rgt = re[r];

        float4 o;
        o.x = k1 * (up.x + dn.x + lft  + cc.y) + k4 * cc.x;
        o.y = k1 * (up.y + dn.y + cc.x + cc.z) + k4 * cc.y;
        o.z = k1 * (up.z + dn.z + cc.y + cc.w) + k4 * cc.z;
        o.w = k1 * (up.w + dn.w + cc.z + rgt ) + k4 * cc.w;
        *reinterpret_cast<float4*>(outp + r * NY) = o;
    }
}

extern "C" void kernel_launch(void* const* d_in, const int* in_sizes, int n_in,
                              void* d_out, int out_size, void* d_ws, size_t ws_size,
                              hipStream_t stream) {
    const float* u_main    = (const float*)d_in[0];
    // d_in[1] = u_coupled (unused)
    const float* D_eff     = (const float*)d_in[2];
    const float* dirichlet = (const float*)d_in[3];
    const float* stencil   = (const float*)d_in[4];
    // d_in[5] = t (unused)
    float* outp = (float*)d_out;

    // (4096/ROWS)=256 bands x 4 column-groups = 1024 blocks of 256 threads
    const int grid  = 1024;    // 4 blocks/CU
    const int block = 256;

    flux_stencil_kernel<<<grid, block, 0, stream>>>(u_main, D_eff, dirichlet, stencil, outp);
}

// Round 8
// 26.152 us; speedup vs baseline: 1.2219x; 1.0354x over previous
//
#include <hip/hip_runtime.h>

// Flux_Kernels: 5-point stencil with Dirichlet BCs on all 4 sides.
// out[i,j] = D * ( s0*(nUp + nDown + nLeft + nRight) + 4*s1*u[i,j] )
// Off-grid neighbors -> dirichlet_val[{0,1,2,3}] for {i=0, i=NX-1, j=0, j=NY-1}.
//
// Round-8: fully UNIFORM row loop. R7's VGPR=40 proved the compiler collapsed
// the prefetch pipeline and sank the lane-predicated edge loads + DS shuffles
// into the loop (per-row latency bubble -> stuck at ~5.0 TB/s CU traffic vs
// 6.3 copy ceiling). Now each row is reconstructed from TWO dword-aligned
// overlapping float4 loads (A at j-1, B at j+1): cc=(A.y,A.z,A.w,B.z),
// lft=A.x, rgt=B.w. Grid edges via per-thread clamped offsets + cndmask
// selects -- no shuffles, no divergent loads, pure {2 loads, VALU, 1 store}
// stream, software-pipelined at distance 4 rows (constant-indexed arrays,
// fully unrolled). XCD swizzle as R7.

#define NX 4096
#define NY 4096
#define ROWS 16
#define PF 4                 // prefetch distance (rows)
#define SLOTS (ROWS + 2)     // slot k holds row i0 + k - 1 (k=0 -> halo above)

typedef float float4v __attribute__((ext_vector_type(4)));
typedef float float4a __attribute__((ext_vector_type(4), aligned(4)));

__global__ __launch_bounds__(256) void flux_stencil_kernel(
    const float* __restrict__ u,
    const float* __restrict__ D_eff,
    const float* __restrict__ dv,
    const float* __restrict__ st,
    float* __restrict__ out)
{
    const float D  = D_eff[0];
    const float s0 = st[0];
    const float s1 = st[1];
    const float k1 = D * s0;         // neighbor coefficient
    const float k4 = 4.0f * D * s1;  // center coefficient
    const float dvUp = dv[0], dvDn = dv[1], dvL = dv[2], dvR = dv[3];

    // XCD-aware bijective swizzle over 1024 blocks (XCD = hw%8):
    const int hw   = blockIdx.x;
    const int x    = hw & 7;
    const int band = ((x & 1) << 7) + (hw >> 3);   // [0,256)
    const int cg   = x >> 1;                       // [0,4)
    const int w    = threadIdx.x >> 6;             // wave in block [0,4)
    const int lane = threadIdx.x & 63;
    const int j    = cg * 1024 + w * 256 + lane * 4;
    const int i0   = band * ROWS;

    const bool fL = (j == 0);
    const bool fR = (j + 4 == NY);
    const int  aO = fL ? 0 : -1;     // A-load column offset (clamped at left edge)
    const int  bO = fR ? 0 : 1;      // B-load column offset (clamped at right edge)
    const bool topEdge = (i0 == 0);
    const bool botEdge = (i0 + ROWS == NX);

    const float* base = u   + (size_t)i0 * NY + j;   // row i0, col j
    float*       outp = out + (size_t)i0 * NY + j;

    float4v A[SLOTS], B[SLOTS];      // raw overlapping loads per slot
    float4v cc[SLOTS];               // reconstructed 4-wide center values
    float   lf[SLOTS], rg[SLOTS];    // left/right neighbors per slot

    // ---- issue: slot k covers grid row (i0 + k - 1), clamped at grid ends ----
    #define ISSUE(k)                                                           \
    {                                                                          \
        int rr = (k) - 1;                                                      \
        if ((k) == 0 && topEdge)          rr = 0;        /* row -1 clamp */    \
        if ((k) == ROWS + 1 && botEdge)   rr = ROWS - 1; /* row NX clamp */    \
        const float* p = base + (ptrdiff_t)rr * NY;                            \
        A[k] = *reinterpret_cast<const float4a*>(p + aO);                      \
        B[k] = *reinterpret_cast<const float4a*>(p + bO);                      \
    }

    // ---- reconstruct slot k: cc, lf, rg from A/B with edge selects ----
    #define RECON(k)                                                           \
    {                                                                          \
        const float4v a = A[k], b = B[k];                                      \
        float4v c;                                                             \
        c.x = fL ? a.x : a.y;                                                  \
        c.y = fL ? a.y : a.z;                                                  \
        c.z = fL ? a.z : a.w;                                                  \
        c.w = fR ? b.w : b.z;                                                  \
        lf[k] = fL ? dvL : a.x;                                                \
        rg[k] = fR ? dvR : b.w;                                                \
        if ((k) == 0 && topEdge)        { c.x = dvUp; c.y = dvUp; c.z = dvUp; c.w = dvUp; } \
        if ((k) == ROWS + 1 && botEdge) { c.x = dvDn; c.y = dvDn; c.z = dvDn; c.w = dvDn; } \
        cc[k] = c;                                                             \
    }

    // ---- compute + store center slot (k-1) once cc[k] is available ----
    #define STORE(k)                                                           \
    {                                                                          \
        const float4v up = cc[(k) - 2], c = cc[(k) - 1], dn = cc[k];           \
        const float l = lf[(k) - 1], r = rg[(k) - 1];                          \
        float4v o;                                                             \
        o.x = k1 * (up.x + dn.x + l   + c.y) + k4 * c.x;                       \
        o.y = k1 * (up.y + dn.y + c.x + c.z) + k4 * c.y;                       \
        o.z = k1 * (up.z + dn.z + c.y + c.w) + k4 * c.z;                       \
        o.w = k1 * (up.w + dn.w + c.z + r  ) + k4 * c.w;                       \
        *reinterpret_cast<float4v*>(outp + (size_t)((k) - 2) * NY) = o;        \
    }

    #pragma unroll
    for (int k = 0; k < PF; ++k) ISSUE(k)

    #pragma unroll
    for (int k = 0; k < SLOTS; ++k) {
        if (k + PF < SLOTS) ISSUE(k + PF)
        RECON(k)
        if (k >= 2) STORE(k)
    }

    #undef ISSUE
    #undef RECON
    #undef STORE
}

extern "C" void kernel_launch(void* const* d_in, const int* in_sizes, int n_in,
                              void* d_out, int out_size, void* d_ws, size_t ws_size,
                              hipStream_t stream) {
    const float* u_main    = (const float*)d_in[0];
    // d_in[1] = u_coupled (unused)
    const float* D_eff     = (const float*)d_in[2];
    const float* dirichlet = (const float*)d_in[3];
    const float* stencil   = (const float*)d_in[4];
    // d_in[5] = t (unused)
    float* outp = (float*)d_out;

    // (4096/ROWS)=256 bands x 4 column-groups = 1024 blocks of 256 threads
    const int grid  = 1024;    // 4 blocks/CU, 16 waves/CU
    const int block = 256;

    flux_stencil_kernel<<<grid, block, 0, stream>>>(u_main, D_eff, dirichlet, stencil, outp);
}

// Round 10
// 26.059 us; speedup vs baseline: 1.2262x; 1.0036x over previous
//
#include <hip/hip_runtime.h>

// Flux_Kernels: 5-point stencil with Dirichlet BCs on all 4 sides.
// out[i,j] = D * ( s0*(nUp + nDown + nLeft + nRight) + 4*s1*u[i,j] )
// Off-grid neighbors -> dirichlet_val[{0,1,2,3}] for {i=0, i=NX-1, j=0, j=NY-1}.
//
// Round-10: R8's uniform dataflow (two overlapping dword-aligned loads per
// row, cndmask edge handling, no DS ops, no divergent loads) with the load
// pipeline pinned by sched_barrier(0) REGION FENCES instead of R9's volatile
// asm (which faulted: forced dwordx4 on 4B-aligned addresses + hand-counted
// vmcnt desynced from compiler stores). Loads remain normal HIP loads - the
// compiler keeps legal encodings and inserts its own exact counted vmcnt -
// but the scheduler can no longer sink ISSUE(k+PF) below the fence toward
// RECON(k+PF) four slots later; the 4-slot in-flight window (8 loads,
// ~8 KiB/wave) must stay live. launch_bounds(256,4) caps VGPR at 128 so the
// window fits without spilling (R6-R8 all collapsed to VGPR<=60 => ~2 loads
// in flight => each row serialized behind a fresh HBM latency at ~5.3 TB/s
// composite vs the 6.3 TB/s copy ceiling).

#define NX 4096
#define NY 4096
#define ROWS 16
#define PF 4                 // prefetch distance (slots in flight)
#define SLOTS (ROWS + 2)     // slot k holds grid row i0 + k - 1

typedef float float4v __attribute__((ext_vector_type(4)));
typedef float float4a __attribute__((ext_vector_type(4), aligned(4)));

__global__ __launch_bounds__(256, 4) void flux_stencil_kernel(
    const float* __restrict__ u,
    const float* __restrict__ D_eff,
    const float* __restrict__ dv,
    const float* __restrict__ st,
    float* __restrict__ out)
{
    const float D  = D_eff[0];
    const float s0 = st[0];
    const float s1 = st[1];
    const float k1 = D * s0;         // neighbor coefficient
    const float k4 = 4.0f * D * s1;  // center coefficient
    const float dvUp = dv[0], dvDn = dv[1], dvL = dv[2], dvR = dv[3];

    // XCD-aware bijective swizzle over 1024 blocks (XCD = hw%8):
    const int hw   = blockIdx.x;
    const int x    = hw & 7;
    const int band = ((x & 1) << 7) + (hw >> 3);   // [0,256)
    const int cg   = x >> 1;                       // [0,4)
    const int w    = threadIdx.x >> 6;             // wave in block [0,4)
    const int lane = threadIdx.x & 63;
    const int j    = cg * 1024 + w * 256 + lane * 4;
    const int i0   = band * ROWS;

    const bool fL = (j == 0);
    const bool fR = (j + 4 == NY);
    const int  aO = fL ? 0 : -1;     // A-load col offset (clamped at left edge)
    const int  bO = fR ? 0 : 1;      // B-load col offset (clamped at right edge)
    const bool topEdge = (i0 == 0);
    const bool botEdge = (i0 + ROWS == NX);

    const float* base = u   + (size_t)i0 * NY + j;   // row i0, col j
    float*       outp = out + (size_t)i0 * NY + j;

    float4v A[SLOTS], B[SLOTS];      // raw overlapping loads per slot
    float4v cc[SLOTS];               // reconstructed 4-wide center values
    float   lf[SLOTS], rg[SLOTS];    // left/right neighbors per slot

    // ---- issue: slot k covers grid row (i0 + k - 1), clamped at grid ends ----
    #define ISSUE(k)                                                           \
    {                                                                          \
        int rr = (k) - 1;                                                      \
        if ((k) == 0 && topEdge)         rr = 0;        /* row -1 clamp */     \
        if ((k) == SLOTS - 1 && botEdge) rr = ROWS - 1; /* row NX clamp */     \
        const float* p = base + (ptrdiff_t)rr * NY;                            \
        A[k] = *reinterpret_cast<const float4a*>(p + aO);                      \
        B[k] = *reinterpret_cast<const float4a*>(p + bO);                      \
    }

    // ---- reconstruct slot k: cc, lf, rg from A/B with edge selects ----
    #define RECON(k)                                                           \
    {                                                                          \
        const float4v a = A[k], b = B[k];                                      \
        float4v c;                                                             \
        c.x = fL ? a.x : a.y;                                                  \
        c.y = fL ? a.y : a.z;                                                  \
        c.z = fL ? a.z : a.w;                                                  \
        c.w = fR ? b.w : b.z;                                                  \
        lf[k] = fL ? dvL : a.x;                                                \
        rg[k] = fR ? dvR : b.w;                                                \
        if ((k) == 0 && topEdge)         { c.x = dvUp; c.y = dvUp; c.z = dvUp; c.w = dvUp; } \
        if ((k) == SLOTS - 1 && botEdge) { c.x = dvDn; c.y = dvDn; c.z = dvDn; c.w = dvDn; } \
        cc[k] = c;                                                             \
    }

    // ---- compute + store center row (k-1) once cc[k] is available ----
    #define STORE(k)                                                           \
    {                                                                          \
        const float4v up = cc[(k) - 2], c = cc[(k) - 1], dn = cc[k];           \
        const float l = lf[(k) - 1], r = rg[(k) - 1];                          \
        float4v o;                                                             \
        o.x = k1 * (up.x + dn.x + l   + c.y) + k4 * c.x;                       \
        o.y = k1 * (up.y + dn.y + c.x + c.z) + k4 * c.y;                       \
        o.z = k1 * (up.z + dn.z + c.y + c.w) + k4 * c.z;                       \
        o.w = k1 * (up.w + dn.w + c.z + r  ) + k4 * c.w;                       \
        *reinterpret_cast<float4v*>(outp + (size_t)((k) - 2) * NY) = o;        \
    }

    // prologue: fill pipeline with slots 0..PF-1, then fence
    #pragma unroll
    for (int k = 0; k < PF; ++k) ISSUE(k)
    __builtin_amdgcn_sched_barrier(0);

    // steady state: each region = {issue slot k+PF} fence {consume slot k}
    #pragma unroll
    for (int k = 0; k < SLOTS; ++k) {
        if (k + PF < SLOTS) ISSUE(k + PF)
        __builtin_amdgcn_sched_barrier(0);   // loads above cannot sink below
        RECON(k)
        if (k >= 2) STORE(k)
        __builtin_amdgcn_sched_barrier(0);   // consumes cannot drift across regions
    }

    #undef ISSUE
    #undef RECON
    #undef STORE
}

extern "C" void kernel_launch(void* const* d_in, const int* in_sizes, int n_in,
                              void* d_out, int out_size, void* d_ws, size_t ws_size,
                              hipStream_t stream) {
    const float* u_main    = (const float*)d_in[0];
    // d_in[1] = u_coupled (unused)
    const float* D_eff     = (const float*)d_in[2];
    const float* dirichlet = (const float*)d_in[3];
    const float* stencil   = (const float*)d_in[4];
    // d_in[5] = t (unused)
    float* outp = (float*)d_out;

    // (4096/ROWS)=256 bands x 4 column-groups = 1024 blocks of 256 threads
    const int grid  = 1024;    // 4 blocks/CU, 16 waves/CU
    const int block = 256;

    flux_stencil_kernel<<<grid, block, 0, stream>>>(u_main, D_eff, dirichlet, stencil, outp);
}